// Round 4
// baseline (902.706 us; speedup 1.0000x reference)
//
#include <hip/hip_runtime.h>
#include <math.h>

#define T_STEPS 64
#define B_ENVS 128
#define L_TOK 64
#define E_DIM 256
#define H_DIM 32
#define N_SEQ (T_STEPS * B_ENVS)   // 8192
#define G4H 128                    // 4*H

// LDS bf16 tile row stride: 264 elems = 132 words; 132 % 32 = 4.
// For the wave's b128 fragment reads (16 rows x 4 quads), start-slot =
// (r + q) mod 8 -> exactly 8 lanes per 16B slot = 8 accesses/bank = the
// balanced optimum for a 1 KB wave read. No conflict pathology here.
#define BSTRIDE 264

typedef __bf16 bf16x8 __attribute__((ext_vector_type(8)));
typedef __bf16 bf16x4 __attribute__((ext_vector_type(4)));
typedef float f32x4 __attribute__((ext_vector_type(4)));

// ---------------------------------------------------------------------------
// K0a: Mtb[f][e] = bf16( (1/16) * sum_c ipw[c][e] * ipw[E+c][f] )  (= M[e][f])
// ---------------------------------------------------------------------------
__global__ void k_precompute_M(const float* __restrict__ ipw, __bf16* __restrict__ Mtb) {
    const int e = blockIdx.x;
    const int f = threadIdx.x;
    float acc = 0.f;
    for (int c = 0; c < E_DIM; ++c) {
        acc = fmaf(ipw[c * E_DIM + e], ipw[(E_DIM + c) * E_DIM + f], acc);
    }
    Mtb[f * E_DIM + e] = (__bf16)(acc * (1.0f / 16.0f));
}

// ---------------------------------------------------------------------------
// K0b: R[g][e] = sum_{e'} w_ih[g][e'] * Wo[e'][e]
// ---------------------------------------------------------------------------
__global__ void k_precompute_R(const float* __restrict__ w_ih,
                               const float* __restrict__ opw,
                               float* __restrict__ R) {
    const int g = blockIdx.x;
    const int e = threadIdx.x;
    float acc = 0.f;
    for (int ep = 0; ep < E_DIM; ++ep) {
        acc = fmaf(w_ih[g * E_DIM + ep], opw[ep * E_DIM + e], acc);
    }
    R[g * E_DIM + e] = acc;
}

// ---------------------------------------------------------------------------
// K0c: Q[i][g] = sum_e Wv[e][i] * R[g][e]
// ---------------------------------------------------------------------------
__global__ void k_precompute_Q(const float* __restrict__ ipw,
                               const float* __restrict__ R,
                               float* __restrict__ Q) {
    const int g = blockIdx.x;
    const int i = threadIdx.x;
    float acc = 0.f;
    for (int e = 0; e < E_DIM; ++e) {
        acc = fmaf(ipw[(2 * E_DIM + e) * E_DIM + i], R[g * E_DIM + e], acc);
    }
    Q[i * G4H + g] = acc;
}

// ---------------------------------------------------------------------------
// K1: per-sequence fused attention. 1024 threads (16 waves), 2 blocks/CU.
//   __launch_bounds__(1024,8) => 64-VGPR hard cap. GEMM loops use
//   #pragma unroll 2 to keep peak live values ~45 VGPRs (16 acc + 2 bfrag
//   windows + afrag + addressing) so the allocator meets the cap WITHOUT
//   spilling to scratch. Full unroll wanted ~75+ live -> silent spill risk.
// ---------------------------------------------------------------------------
__global__ __launch_bounds__(1024, 8) void k_attn(const float* __restrict__ x,
                                                  const int* __restrict__ obs_mask,
                                                  const __bf16* __restrict__ Mtb,
                                                  const float* __restrict__ Q,
                                                  float* __restrict__ gates_x) {
    __shared__ __align__(16) __bf16 xb[L_TOK * BSTRIDE];    // 33792 B
    __shared__ __align__(16) __bf16 ybuf[L_TOK * BSTRIDE];  // 33792 B (reused for E/F)
    __shared__ float dropped[64];    // reused as wsum[] after B3
    __shared__ float pcol[4][64];

    // Overlays on ybuf (safe: two barriers separate last yb read from first write)
    float* upart = (float*)ybuf;           // [4][256] = 4096 B
    float* u_l   = (float*)ybuf + 1024;    // [256]    = 1024 B
    float* gpart = (float*)ybuf + 1280;    // [8][128] = 4096 B

    const int n = blockIdx.x;
    const int t = threadIdx.x;
    const int lane = t & 63;
    const int w = t >> 6;            // wave id 0..15
    const int lane15 = lane & 15;
    const int quad = lane >> 4;      // 0..3
    const float* xn = x + (size_t)n * (L_TOK * E_DIM);

    if (t < 64) dropped[t] = (obs_mask[n * L_TOK + t] == 0) ? 1.0f : 0.0f;

    // ---- stage x -> bf16 LDS (coalesced float4 reads) ----
    {
        const float4* x4 = (const float4*)xn;
#pragma unroll
        for (int it = 0; it < 4; ++it) {
            const int flat4 = t + 1024 * it;
            const int row = flat4 >> 6;
            const int col = (flat4 & 63) * 4;
            const float4 v = x4[flat4];
            bf16x4 pk;
            pk.x = (__bf16)v.x; pk.y = (__bf16)v.y;
            pk.z = (__bf16)v.z; pk.w = (__bf16)v.w;
            *(bf16x4*)&xb[row * BSTRIDE + col] = pk;
        }
    }
    __syncthreads();                                           // B1

    // ---- GEMM1: y = xb @ M ; wave w -> y[:, 16w..16w+15] ----
    {
        f32x4 acc1[4];
#pragma unroll
        for (int rt = 0; rt < 4; ++rt) acc1[rt] = (f32x4)0.f;

        const __bf16* mrow = Mtb + (size_t)(16 * w + lane15) * E_DIM;
#pragma unroll 2
        for (int kc = 0; kc < 8; ++kc) {
            const int kofs = kc * 32 + quad * 8;
            const bf16x8 bfrag = *(const bf16x8*)(mrow + kofs);
#pragma unroll
            for (int rt = 0; rt < 4; ++rt) {
                const bf16x8 afrag = *(const bf16x8*)&xb[(16 * rt + lane15) * BSTRIDE + kofs];
                acc1[rt] = __builtin_amdgcn_mfma_f32_16x16x32_bf16(afrag, bfrag, acc1[rt], 0, 0, 0);
            }
        }
        // C-layout: row = 16rt + 4*quad + r, col = 16w + lane15
#pragma unroll
        for (int rt = 0; rt < 4; ++rt) {
            const int col = 16 * w + lane15;
#pragma unroll
            for (int r = 0; r < 4; ++r)
                ybuf[(16 * rt + 4 * quad + r) * BSTRIDE + col] = (__bf16)acc1[rt][r];
        }
    }
    __syncthreads();                                           // B2

    // ---- GEMM2 + softmax + colsum: waves 0..3 only ----
    if (w < 4) {
        f32x4 acc2[4];
#pragma unroll
        for (int ct = 0; ct < 4; ++ct) acc2[ct] = (f32x4)0.f;
#pragma unroll 2
        for (int kc = 0; kc < 8; ++kc) {
            const int kofs = kc * 32 + quad * 8;
            const bf16x8 a2 = *(const bf16x8*)&ybuf[(16 * w + lane15) * BSTRIDE + kofs];
#pragma unroll
            for (int ct = 0; ct < 4; ++ct) {
                const bf16x8 b2 = *(const bf16x8*)&xb[(16 * ct + lane15) * BSTRIDE + kofs];
                acc2[ct] = __builtin_amdgcn_mfma_f32_16x16x32_bf16(a2, b2, acc2[ct], 0, 0, 0);
            }
        }
        float db[4];
#pragma unroll
        for (int ct = 0; ct < 4; ++ct) db[ct] = dropped[16 * ct + lane15];
        float colpart[4] = {0.f, 0.f, 0.f, 0.f};
#pragma unroll
        for (int r = 0; r < 4; ++r) {
            const float da = dropped[16 * w + 4 * quad + r];
            float s[4];
#pragma unroll
            for (int ct = 0; ct < 4; ++ct) {
                s[ct] = acc2[ct][r];
                if (da > 0.5f && db[ct] > 0.5f) s[ct] = -1e9f;
            }
            float mx = fmaxf(fmaxf(s[0], s[1]), fmaxf(s[2], s[3]));
#pragma unroll
            for (int off = 1; off < 16; off <<= 1) mx = fmaxf(mx, __shfl_xor(mx, off));
            float p[4], ssum = 0.f;
#pragma unroll
            for (int ct = 0; ct < 4; ++ct) { p[ct] = __expf(s[ct] - mx); ssum += p[ct]; }
#pragma unroll
            for (int off = 1; off < 16; off <<= 1) ssum += __shfl_xor(ssum, off);
            const float inv = 1.0f / ssum;
#pragma unroll
            for (int ct = 0; ct < 4; ++ct) colpart[ct] = fmaf(p[ct], inv, colpart[ct]);
        }
#pragma unroll
        for (int ct = 0; ct < 4; ++ct) {
            float cp = colpart[ct];
            cp += __shfl_xor(cp, 16);
            cp += __shfl_xor(cp, 32);
            colpart[ct] = cp;
        }
        if (quad == 0) {
#pragma unroll
            for (int ct = 0; ct < 4; ++ct) pcol[w][16 * ct + lane15] = colpart[ct];
        }
    }
    __syncthreads();                                           // B3

    // ---- wsum precompute: dropped[] is dead after B3, reuse as wsum ----
    // Cuts phase E from 64 pcol reads/thread to 16 wsum reads/thread
    // (~768 fewer LDS wave-insts per block).
    if (t < 64) dropped[t] = pcol[0][t] + pcol[1][t] + pcol[2][t] + pcol[3][t];
    __syncthreads();                                           // B3b

    // ---- phase E: u[i] = sum_k wsum[k] * xb[k][i] ----
    {
        const int i = t & 255;
        const int kg = t >> 8;       // 0..3
        float acc = 0.f;
#pragma unroll
        for (int k = 16 * kg; k < 16 * kg + 16; ++k) {
            acc = fmaf(dropped[k], (float)xb[k * BSTRIDE + i], acc);
        }
        upart[kg * 256 + i] = acc;
    }
    __syncthreads();                                           // B4
    if (t < 256)
        u_l[t] = upart[t] + upart[256 + t] + upart[512 + t] + upart[768 + t];
    __syncthreads();                                           // B5

    // ---- phase F: gates_x[n][g] = sum_i u[i] * Q[i][g] ----
    {
        const int g = t & 127;
        const int q = t >> 7;        // 0..7
        float acc = 0.f;
#pragma unroll
        for (int i = 32 * q; i < 32 * q + 32; ++i)
            acc = fmaf(u_l[i], Q[i * G4H + g], acc);
        gpart[q * 128 + g] = acc;
    }
    __syncthreads();                                           // B6
    if (t < 128) {
        float gx = 0.f;
#pragma unroll
        for (int q = 0; q < 8; ++q) gx += gpart[q * 128 + t];
        gates_x[(size_t)n * G4H + t] = gx;
    }
}

// ---------------------------------------------------------------------------
// K2: per-env LSTM, ONE WAVE per env. No LDS, no barriers.
// Lane l owns gates l (i/f) and 64+l (g/o). h lives in lanes 0..31, broadcast
// via __shfl. Next step's gates_x/done prefetched before the dot chain.
// ---------------------------------------------------------------------------
__device__ __forceinline__ float sigmoidf_(float v) {
    return 1.0f / (1.0f + __expf(-v));
}
__device__ __forceinline__ float tanh_safe(float v) {
    const float av = fabsf(v);
    const float e = __expf(-2.0f * av);
    const float r = (1.0f - e) / (1.0f + e);
    return v < 0.f ? -r : r;
}

__global__ __launch_bounds__(64) void k_lstm(const float* __restrict__ gates_x,
                                             const float* __restrict__ done,
                                             const float* __restrict__ h0,
                                             const float* __restrict__ c0,
                                             const float* __restrict__ w_hh,
                                             const float* __restrict__ b_ih,
                                             const float* __restrict__ b_hh,
                                             const float* __restrict__ critic_w,
                                             const float* __restrict__ critic_b,
                                             float* __restrict__ out) {
    const int b = blockIdx.x;
    const int l = threadIdx.x;        // 0..63
    const int g0 = l;
    const int g1 = 64 + l;

    float wr0[H_DIM], wr1[H_DIM];
#pragma unroll
    for (int k = 0; k < H_DIM; ++k) {
        wr0[k] = w_hh[g0 * H_DIM + k];
        wr1[k] = w_hh[g1 * H_DIM + k];
    }
    const float bs0 = b_ih[g0] + b_hh[g0];
    const float bs1 = b_ih[g1] + b_hh[g1];

    float h_reg = (l < H_DIM) ? h0[b * H_DIM + l] : 0.f;
    float c_reg = (l < H_DIM) ? c0[b * H_DIM + l] : 0.f;
    const float cw = (l < H_DIM) ? critic_w[l] : 0.f;
    const float cb = critic_b[0];

    // prefetch step 0
    float nx0 = gates_x[(size_t)b * G4H + g0];
    float nx1 = gates_x[(size_t)b * G4H + g1];
    float nd  = done[b];

    for (int step = 0; step < T_STEPS; ++step) {
        const float gx0 = nx0, gx1 = nx1, dv = nd;
        // prefetch step+1 (clamped; redundant refetch on last step is harmless)
        const int ns = (step + 1 < T_STEPS) ? step + 1 : step;
        const size_t nb = (size_t)(ns * B_ENVS + b) * G4H;
        nx0 = gates_x[nb + g0];
        nx1 = gates_x[nb + g1];
        nd  = done[ns * B_ENVS + b];

        const float keep = 1.0f - dv;
        float d0 = 0.f, d1 = 0.f;
#pragma unroll
        for (int k = 0; k < H_DIM; ++k) {
            const float hk = __shfl(h_reg, k);
            d0 = fmaf(hk, wr0[k], d0);
            d1 = fmaf(hk, wr1[k], d1);
        }
        const float pre0 = gx0 + bs0 + keep * d0;
        const float pre1 = gx1 + bs1 + keep * d1;

        const float act0 = sigmoidf_(pre0);                    // i (l<32) / f (l>=32)
        const float act1 = (l < 32) ? tanh_safe(pre1)          // g
                                    : sigmoidf_(pre1);         // o
        const float fv = __shfl_xor(act0, 32);
        const float ov = __shfl_xor(act1, 32);

        c_reg = fmaf(fv, keep * c_reg, act0 * act1);           // valid for l<32
        h_reg = ov * tanh_safe(c_reg);
        float val = h_reg * cw;                                // cw=0 for l>=32
#pragma unroll
        for (int off = 1; off < 32; off <<= 1) val += __shfl_xor(val, off);
        if (l == 0) out[step * B_ENVS + b] = val + cb;
    }
}

// ---------------------------------------------------------------------------
extern "C" void kernel_launch(void* const* d_in, const int* in_sizes, int n_in,
                              void* d_out, int out_size, void* d_ws, size_t ws_size,
                              hipStream_t stream) {
    const float* x    = (const float*)d_in[0];
    const float* done = (const float*)d_in[1];
    const int* mask   = (const int*)d_in[2];
    const float* h0   = (const float*)d_in[3];
    const float* c0   = (const float*)d_in[4];
    const float* ipw  = (const float*)d_in[5];
    const float* opw  = (const float*)d_in[6];
    const float* w_ih = (const float*)d_in[7];
    const float* w_hh = (const float*)d_in[8];
    const float* b_ih = (const float*)d_in[9];
    const float* b_hh = (const float*)d_in[10];
    const float* cw   = (const float*)d_in[11];
    const float* cb   = (const float*)d_in[12];
    float* out = (float*)d_out;

    char* ws = (char*)d_ws;
    __bf16* Mtb = (__bf16*)(ws);                    // 128 KB
    float* R    = (float*)(ws + (128 * 1024));      // 128 KB
    float* Q    = (float*)(ws + (256 * 1024));      // 128 KB
    float* gx   = (float*)(ws + (384 * 1024));      // 4 MB

    k_precompute_M<<<256, 256, 0, stream>>>(ipw, Mtb);
    k_precompute_R<<<128, 256, 0, stream>>>(w_ih, opw, R);
    k_precompute_Q<<<128, 256, 0, stream>>>(ipw, R, Q);
    k_attn<<<N_SEQ, 1024, 0, stream>>>(x, mask, Mtb, Q, gx);
    k_lstm<<<B_ENVS, 64, 0, stream>>>(gx, done, h0, c0, w_hh, b_ih, b_hh, cw, cb, out);
}